// Round 5
// baseline (89.047 us; speedup 1.0000x reference)
//
#include <hip/hip_runtime.h>

#define IN_F   4096
#define OUT_F  11008
#define BATCH  32
#define NG     32      // K groups of 128
#define PACKS  512     // IN/8 packed ints per output row
#define SLICES 16      // K-partial slices (4 kc-chunks x 4 waves)
#define SLICE_F (BATCH * OUT_F)   // floats per partial slice (352256)

typedef __bf16 bf16x8_t __attribute__((ext_vector_type(8)));
typedef float  floatx4_t __attribute__((ext_vector_type(4)));

// ---------------------------------------------------------------------------
// Prep: x fp32 [32,4096] -> bf16, reordered so main-kernel A-fragment loads are
// lane-contiguous 16B/lane (harness-verified since round 0).
// Chunk c (16384 total), 8 elems each:
//   mm=c&31, q=(c>>5)&3, t=(c>>7)&3, g=c>>9
//   xp[c*8+j] = bf16( x[mm][g*128 + q*32 + t*8 + j] )
// ---------------------------------------------------------------------------
__global__ __launch_bounds__(256) void prep_x(const float* __restrict__ x,
                                              unsigned short* __restrict__ xp) {
  int c  = blockIdx.x * 256 + threadIdx.x;      // 0..16383
  int mm = c & 31;
  int k0 = ((c >> 5) & 3) * 32 + ((c >> 7) & 3) * 8 + (c >> 9) * 128;
  const float* src = x + mm * IN_F + k0;
  float4 f0 = *(const float4*)(src);
  float4 f1 = *(const float4*)(src + 4);
  float v[8] = {f0.x, f0.y, f0.z, f0.w, f1.x, f1.y, f1.z, f1.w};
  union { unsigned short s[8]; uint4 u; } r;
#pragma unroll
  for (int j = 0; j < 8; ++j) {
    unsigned int u = __float_as_uint(v[j]);
    unsigned int rnd = ((u >> 16) & 1u) + 0x7fffu;   // RNE fp32->bf16
    r.s[j] = (unsigned short)((u + rnd) >> 16);
  }
  *(uint4*)(xp + c * 8) = r.u;
}

// signed int4 nibbles (low nibble first) -> 8 exact bf16 values (no scale)
__device__ inline bf16x8_t unpack8(int p) {
  union { unsigned short u[8]; bf16x8_t v; } r;
#pragma unroll
  for (int j = 0; j < 8; ++j) {
    int nib = (p << (28 - 4 * j)) >> 28;             // arithmetic sign-extend
    float f = (float)nib;                            // exact
    r.u[j] = (unsigned short)(__float_as_uint(f) >> 16);  // exact truncation
  }
  return r.v;
}

__device__ inline bf16x8_t load_frag(const unsigned short* p) {
  union { uint4 u; bf16x8_t v; } x;
  x.u = *(const uint4*)p;
  return x.v;
}

// ---------------------------------------------------------------------------
// Stage 1: K-split-16 partials, ATOMIC-FREE (round-4 post-mortem: the 1.4M
// device-scope fp32 atomics with 4-way cross-XCD contention + the LDS/sync
// epilogue + the serialized init_out were the residual ~10us, not the math).
// Grid (344 col-tiles) x (4 kc). Block = 4 INDEPENDENT waves (no LDS, no
// __syncthreads): wave w computes groups kc*8 + 2w + {0,1} for 32 cols and
// stores its private 32x32 fp32 partial tile to ws slice (kc*4+w) with plain
// dword stores. d_ws is poisoned by the harness unconditionally every
// iteration (measured R3/R4), so workspace use is free.
// Inner math loop identical to the verified round-4 kernel (52 VGPR <= 64
// keeps the 8-waves/SIMD occupancy cap).
// ---------------------------------------------------------------------------
__global__ __launch_bounds__(256) void wql_part(
    const int* __restrict__ pw, const float* __restrict__ scale,
    const unsigned short* __restrict__ xp, float* __restrict__ part) {
  const int tid = threadIdx.x;
  const int l   = tid & 63;
  const int w   = tid >> 6;
  const int col = l & 15;
  const int q   = l >> 4;
  const int n0  = blockIdx.x * 32;
  const int kc  = blockIdx.y;      // 0..3 K-chunk
  const int nA  = n0 + col;        // n-tile 0 column
  const int nB  = n0 + 16 + col;   // n-tile 1 column

  floatx4_t acc00 = {0.f, 0.f, 0.f, 0.f};
  floatx4_t acc01 = {0.f, 0.f, 0.f, 0.f};
  floatx4_t acc10 = {0.f, 0.f, 0.f, 0.f};
  floatx4_t acc11 = {0.f, 0.f, 0.f, 0.f};

  const int g0 = kc * 8 + w * 2;
#pragma unroll 1
  for (int gi = 0; gi < 2; ++gi) {
    const int gg = g0 + gi;
    // B: one dwordx4 per n-tile = 4 packed ints = this lane's 4 step-fragments
    int4 pA = *(const int4*)(pw + nA * PACKS + gg * 16 + q * 4);
    int4 pB = *(const int4*)(pw + nB * PACKS + gg * 16 + q * 4);
    float sA = scale[nA * NG + gg];
    float sB = scale[nB * NG + gg];

    // A: chunk index = gg*512 + t*128 + q*32 + col (+16 for rows 16..31);
    // consecutive lanes (col,q) -> consecutive 16B chunks: fully coalesced.
    const unsigned short* ab = xp + (gg * 512 + q * 32 + col) * 8;
    bf16x8_t a0[4], a1[4];
#pragma unroll
    for (int t = 0; t < 4; ++t) {
      a0[t] = load_frag(ab + t * 1024);        // rows 0..15
      a1[t] = load_frag(ab + t * 1024 + 128);  // rows 16..31
    }

    floatx4_t t00 = {0.f, 0.f, 0.f, 0.f};
    floatx4_t t01 = {0.f, 0.f, 0.f, 0.f};
    floatx4_t t10 = {0.f, 0.f, 0.f, 0.f};
    floatx4_t t11 = {0.f, 0.f, 0.f, 0.f};
    int pAv[4] = {pA.x, pA.y, pA.z, pA.w};
    int pBv[4] = {pB.x, pB.y, pB.z, pB.w};
#pragma unroll
    for (int t = 0; t < 4; ++t) {
      bf16x8_t b0 = unpack8(pAv[t]);
      bf16x8_t b1 = unpack8(pBv[t]);
      t00 = __builtin_amdgcn_mfma_f32_16x16x32_bf16(a0[t], b0, t00, 0, 0, 0);
      t10 = __builtin_amdgcn_mfma_f32_16x16x32_bf16(a1[t], b0, t10, 0, 0, 0);
      t01 = __builtin_amdgcn_mfma_f32_16x16x32_bf16(a0[t], b1, t01, 0, 0, 0);
      t11 = __builtin_amdgcn_mfma_f32_16x16x32_bf16(a1[t], b1, t11, 0, 0, 0);
    }
    // group scale (per output column; col == lane&15 == C/D col for all regs)
#pragma unroll
    for (int r = 0; r < 4; ++r) {
      acc00[r] += t00[r] * sA;
      acc10[r] += t10[r] * sA;
      acc01[r] += t01[r] * sB;
      acc11[r] += t11[r] * sB;
    }
  }

  // Per-wave private partial slice: no reduction traffic inside the block.
  // C/D layout: col = lane&15, row = quad*4 + reg   [verified m89/m91]
  float* wsp = part + (kc * 4 + w) * SLICE_F + n0;
#pragma unroll
  for (int r = 0; r < 4; ++r) {
    int row = q * 4 + r;
    wsp[row * OUT_F + col]             = acc00[r];
    wsp[row * OUT_F + 16 + col]        = acc01[r];
    wsp[(16 + row) * OUT_F + col]      = acc10[r];
    wsp[(16 + row) * OUT_F + 16 + col] = acc11[r];
  }
}

// ---------------------------------------------------------------------------
// Stage 2: out = sum of 16 partial slices + bias. Fully-coalesced float4
// reads (22.5 MB, L2/L3-resident), one float4 store per thread. Replaces
// init_out + 1.4M contended atomics.
// ---------------------------------------------------------------------------
__global__ __launch_bounds__(256) void reduce_out(
    const float* __restrict__ part, const float* __restrict__ bias,
    float* __restrict__ out) {
  int e4 = blockIdx.x * 256 + threadIdx.x;   // 0..88063 float4s
  int e  = e4 << 2;
  int o  = e % OUT_F;                        // OUT_F % 4 == 0
  float4 s = *(const float4*)(bias + o);
#pragma unroll
  for (int k = 0; k < SLICES; ++k) {
    float4 p = *(const float4*)(part + k * SLICE_F + e);
    s.x += p.x; s.y += p.y; s.z += p.z; s.w += p.w;
  }
  *(float4*)(out + e) = s;
}

extern "C" void kernel_launch(void* const* d_in, const int* in_sizes, int n_in,
                              void* d_out, int out_size, void* d_ws, size_t ws_size,
                              hipStream_t stream) {
  const float* x     = (const float*)d_in[0];
  const int*   pw    = (const int*)d_in[1];
  const float* scale = (const float*)d_in[2];
  const float* bias  = (const float*)d_in[3];
  float* out = (float*)d_out;
  unsigned short* xp = (unsigned short*)d_ws;                  // 256 KiB
  float* part = (float*)((char*)d_ws + (1 << 20));             // 16 x 1.41 MB

  hipLaunchKernelGGL(prep_x, dim3(16384 / 256), dim3(256), 0, stream, x, xp);
  hipLaunchKernelGGL(wql_part, dim3(OUT_F / 32, 4), dim3(256), 0, stream,
                     pw, scale, xp, part);
  hipLaunchKernelGGL(reduce_out, dim3(BATCH * OUT_F / 4 / 256), dim3(256), 0,
                     stream, part, bias, out);
}

// Round 6
// 85.108 us; speedup vs baseline: 1.0463x; 1.0463x over previous
//
#include <hip/hip_runtime.h>

#define IN_F   4096
#define OUT_F  11008
#define BATCH  32
#define NG     32      // K groups of 128
#define PACKS  512     // IN/8 packed ints per output row
#define SLICES 4       // K-partial slices (one per kc chunk)
#define SLICE_F (BATCH * OUT_F)   // floats per partial slice (352256)

typedef __bf16 bf16x8_t __attribute__((ext_vector_type(8)));
typedef float  floatx4_t __attribute__((ext_vector_type(4)));

// ---------------------------------------------------------------------------
// Prep: x fp32 [32,4096] -> bf16, reordered so main-kernel A-fragment loads are
// lane-contiguous 16B/lane (harness-verified since round 0).
// Chunk c (16384 total), 8 elems each:
//   mm=c&31, q=(c>>5)&3, t=(c>>7)&3, g=c>>9
//   xp[c*8+j] = bf16( x[mm][g*128 + q*32 + t*8 + j] )
// ---------------------------------------------------------------------------
__global__ __launch_bounds__(256) void prep_x(const float* __restrict__ x,
                                              unsigned short* __restrict__ xp) {
  int c  = blockIdx.x * 256 + threadIdx.x;      // 0..16383
  int mm = c & 31;
  int k0 = ((c >> 5) & 3) * 32 + ((c >> 7) & 3) * 8 + (c >> 9) * 128;
  const float* src = x + mm * IN_F + k0;
  float4 f0 = *(const float4*)(src);
  float4 f1 = *(const float4*)(src + 4);
  float v[8] = {f0.x, f0.y, f0.z, f0.w, f1.x, f1.y, f1.z, f1.w};
  union { unsigned short s[8]; uint4 u; } r;
#pragma unroll
  for (int j = 0; j < 8; ++j) {
    unsigned int u = __float_as_uint(v[j]);
    unsigned int rnd = ((u >> 16) & 1u) + 0x7fffu;   // RNE fp32->bf16
    r.s[j] = (unsigned short)((u + rnd) >> 16);
  }
  *(uint4*)(xp + c * 8) = r.u;
}

// signed int4 nibbles (low nibble first) -> 8 exact bf16 values (no scale)
__device__ inline bf16x8_t unpack8(int p) {
  union { unsigned short u[8]; bf16x8_t v; } r;
#pragma unroll
  for (int j = 0; j < 8; ++j) {
    int nib = (p << (28 - 4 * j)) >> 28;             // arithmetic sign-extend
    float f = (float)nib;                            // exact
    r.u[j] = (unsigned short)(__float_as_uint(f) >> 16);  // exact truncation
  }
  return r.v;
}

__device__ inline bf16x8_t load_frag(const unsigned short* p) {
  union { uint4 u; bf16x8_t v; } x;
  x.u = *(const uint4*)p;
  return x.v;
}

// ---------------------------------------------------------------------------
// Stage 1. R5 post-mortem: wql_part is latency-exposed (VALUBusy ~12% =
// SIMDs idle 85%) at 21.5 waves/CU with a 2-iteration dependent load chain.
// New shape: ONE group per wave, 8 waves (512 thr) per block, grid 344 x 4kc
// -> 11008 waves (demand 10.75/SIMD, clipped to the 8/SIMD VGPR cap = FULL
// 32 waves/CU), and each wave is a single straight-line load->MFMA phase
// (all loads hoist to the top; one vmcnt wait per wave).
// Epilogue: 8 wave-tiles reduced through LDS to ONE 32x32 partial per
// (col-tile, kc) -> 4 global slices (stage-2 traffic 22.5 -> 5.6 MB).
// d_ws is poisoned unconditionally every iteration (measured R3/R4/R5), so
// workspace use is free. Inner math identical since R0 (absmax 0.125).
// ---------------------------------------------------------------------------
__global__ __launch_bounds__(512) void wql_part(
    const int* __restrict__ pw, const float* __restrict__ scale,
    const unsigned short* __restrict__ xp, float* __restrict__ part) {
  __shared__ float lds[8][BATCH * 32];

  const int tid = threadIdx.x;
  const int l   = tid & 63;
  const int w   = tid >> 6;        // 0..7 = group index within the kc chunk
  const int col = l & 15;
  const int q   = l >> 4;
  const int n0  = blockIdx.x * 32;
  const int kc  = blockIdx.y;      // 0..3 K-chunk
  const int nA  = n0 + col;        // n-tile 0 column
  const int nB  = n0 + 16 + col;   // n-tile 1 column
  const int gg  = kc * 8 + w;      // this wave's group

  // B: one dwordx4 per n-tile = 4 packed ints = this lane's 4 step-fragments
  int4 pA = *(const int4*)(pw + nA * PACKS + gg * 16 + q * 4);
  int4 pB = *(const int4*)(pw + nB * PACKS + gg * 16 + q * 4);
  float sA = scale[nA * NG + gg];
  float sB = scale[nB * NG + gg];

  // A: chunk index = gg*512 + t*128 + q*32 + col (+16 for rows 16..31);
  // consecutive lanes (col,q) -> consecutive 16B chunks: fully coalesced.
  const unsigned short* ab = xp + (gg * 512 + q * 32 + col) * 8;
  bf16x8_t a0[4], a1[4];
#pragma unroll
  for (int t = 0; t < 4; ++t) {
    a0[t] = load_frag(ab + t * 1024);        // rows 0..15
    a1[t] = load_frag(ab + t * 1024 + 128);  // rows 16..31
  }

  floatx4_t t00 = {0.f, 0.f, 0.f, 0.f};
  floatx4_t t01 = {0.f, 0.f, 0.f, 0.f};
  floatx4_t t10 = {0.f, 0.f, 0.f, 0.f};
  floatx4_t t11 = {0.f, 0.f, 0.f, 0.f};
  int pAv[4] = {pA.x, pA.y, pA.z, pA.w};
  int pBv[4] = {pB.x, pB.y, pB.z, pB.w};
#pragma unroll
  for (int t = 0; t < 4; ++t) {
    bf16x8_t b0 = unpack8(pAv[t]);
    bf16x8_t b1 = unpack8(pBv[t]);
    t00 = __builtin_amdgcn_mfma_f32_16x16x32_bf16(a0[t], b0, t00, 0, 0, 0);
    t10 = __builtin_amdgcn_mfma_f32_16x16x32_bf16(a1[t], b0, t10, 0, 0, 0);
    t01 = __builtin_amdgcn_mfma_f32_16x16x32_bf16(a0[t], b1, t01, 0, 0, 0);
    t11 = __builtin_amdgcn_mfma_f32_16x16x32_bf16(a1[t], b1, t11, 0, 0, 0);
  }

  // Scale and park this wave's 32x32 tile in LDS.
  // C/D layout: col = lane&15, row = quad*4 + reg   [verified m89/m91]
#pragma unroll
  for (int r = 0; r < 4; ++r) {
    int row = q * 4 + r;
    lds[w][row * 32 + col]             = t00[r] * sA;
    lds[w][row * 32 + 16 + col]        = t01[r] * sB;
    lds[w][(16 + row) * 32 + col]      = t10[r] * sA;
    lds[w][(16 + row) * 32 + 16 + col] = t11[r] * sB;
  }
  __syncthreads();

  // 512 threads reduce 8 wave-tiles -> 1 partial tile, store to slice kc.
  float* wsp = part + kc * SLICE_F + n0;
  for (int e = tid; e < BATCH * 32; e += 512) {
    int row = e >> 5, cl = e & 31;
    float s = lds[0][e] + lds[1][e] + lds[2][e] + lds[3][e]
            + lds[4][e] + lds[5][e] + lds[6][e] + lds[7][e];
    wsp[row * OUT_F + cl] = s;
  }
}

// ---------------------------------------------------------------------------
// Stage 2: out = sum of 4 partial slices + bias. Fully-coalesced float4
// reads (5.6 MB, L2/L3-resident), one float4 store per thread.
// ---------------------------------------------------------------------------
__global__ __launch_bounds__(256) void reduce_out(
    const float* __restrict__ part, const float* __restrict__ bias,
    float* __restrict__ out) {
  int e4 = blockIdx.x * 256 + threadIdx.x;   // 0..88063 float4s
  int e  = e4 << 2;
  int o  = e % OUT_F;                        // OUT_F % 4 == 0
  float4 s = *(const float4*)(bias + o);
#pragma unroll
  for (int k = 0; k < SLICES; ++k) {
    float4 p = *(const float4*)(part + k * SLICE_F + e);
    s.x += p.x; s.y += p.y; s.z += p.z; s.w += p.w;
  }
  *(float4*)(out + e) = s;
}

extern "C" void kernel_launch(void* const* d_in, const int* in_sizes, int n_in,
                              void* d_out, int out_size, void* d_ws, size_t ws_size,
                              hipStream_t stream) {
  const float* x     = (const float*)d_in[0];
  const int*   pw    = (const int*)d_in[1];
  const float* scale = (const float*)d_in[2];
  const float* bias  = (const float*)d_in[3];
  float* out = (float*)d_out;
  unsigned short* xp = (unsigned short*)d_ws;                  // 256 KiB
  float* part = (float*)((char*)d_ws + (1 << 20));             // 4 x 1.41 MB

  hipLaunchKernelGGL(prep_x, dim3(16384 / 256), dim3(256), 0, stream, x, xp);
  hipLaunchKernelGGL(wql_part, dim3(OUT_F / 32, 4), dim3(512), 0, stream,
                     pw, scale, xp, part);
  hipLaunchKernelGGL(reduce_out, dim3(BATCH * OUT_F / 4 / 256), dim3(256), 0,
                     stream, part, bias, out);
}